// Round 1
// baseline (942.275 us; speedup 1.0000x reference)
//
#include <hip/hip_runtime.h>
#include <math.h>

// Problem constants (from reference): images [64,256,256] f32, vocab [4096,256] f32
// patches out: [64,256,256] f32 (identity permutation of 16x16 patches, raster order)
// tokens out:  [64,256] = argmin_v ||patch - vocab[v]||^2  (written as float)
#define BATCH   64
#define IMG     256
#define PS      16
#define NPP     256              // patches per image (16*16)
#define D       256              // patch dim (16*16)
#define V       4096
#define M       (BATCH * NPP)    // 16384 total patches

// GEMM tiling
#define BM      64
#define BN      64
#define BK      16
#define VSPLIT  4
#define VPB     (V / VSPLIT)     // 1024 vocab rows per block

// fp32 worst-case |s32 - s64| bound is ~2.5e-3; 25x safety margin.
// Expected flagged fraction ~1% (gap distribution: typical top-2 gap ~6.5).
#define MARGIN  0.0625f

// ---------------------------------------------------------------------------
// Kernel 1: patchify — pure permutation, fully coalesced float4 writes.
// patches[b][n][d] = images[b][ (n/16)*16 + d/16 ][ (n%16)*16 + d%16 ]
// ---------------------------------------------------------------------------
__global__ __launch_bounds__(256) void patchify_kernel(
    const float* __restrict__ img, float* __restrict__ out) {
  int t  = blockIdx.x * blockDim.x + threadIdx.x;   // M*D/4 threads
  int o4 = t << 2;
  int b   = o4 >> 16;
  int rem = o4 & 65535;
  int n   = rem >> 8;
  int d   = rem & 255;
  int py = n >> 4, px = n & 15, i = d >> 4, j = d & 15;
  const float4 v = *(const float4*)(img + (b << 16) + ((py * PS + i) << 8) + px * PS + j);
  *(float4*)(out + o4) = v;
}

// ---------------------------------------------------------------------------
// Kernel 2: v2[v] = sum_d vocab[v][d]^2   (one wave64 per vocab row)
// ---------------------------------------------------------------------------
__global__ __launch_bounds__(256) void v2_kernel(
    const float* __restrict__ vocab, float* __restrict__ v2) {
  int gtid = blockIdx.x * blockDim.x + threadIdx.x;
  int row  = gtid >> 6;
  int lane = gtid & 63;
  const float4 x = *(const float4*)(vocab + row * D + (lane << 2));
  float s = x.x * x.x + x.y * x.y + x.z * x.z + x.w * x.w;
  #pragma unroll
  for (int off = 32; off > 0; off >>= 1) s += __shfl_down(s, off);
  if (lane == 0) v2[row] = s;
}

// ---------------------------------------------------------------------------
// Kernel 3: fp32 score GEMM with running top-2 (min1,idx1,min2) per patch.
// Block = 256 threads, computes BM=64 patches x VPB=1024 vocab (16 tiles of 64).
// score = v2[v] - 2*dot(patch, vocab[v])   (x^2 constant per row, dropped)
// ---------------------------------------------------------------------------
__global__ __launch_bounds__(256) void score_kernel(
    const float* __restrict__ A,     // patches [M][D]
    const float* __restrict__ Vc,    // vocab [V][D]
    const float* __restrict__ v2,
    float* __restrict__ pmin1, float* __restrict__ pmin2,
    int* __restrict__ pidx) {
  // +4 pad: rows stay 16B aligned (68 floats = 272B = 17*16) for ds_read_b128,
  // stores land 2-way-conflict max (free on gfx950).
  __shared__ float As[BK][BM + 4];
  __shared__ float Bs[BK][BN + 4];
  __shared__ float sm1[BM][16];
  __shared__ float sm2[BM][16];
  __shared__ int   si1[BM][16];

  const int pb  = blockIdx.x;        // patch block 0..255
  const int vs  = blockIdx.y;        // vocab split 0..VSPLIT-1
  const int tid = threadIdx.x;
  const int tm = tid >> 4;           // 0..15: micro-tile row group
  const int tn = tid & 15;           // 0..15: micro-tile col group

  // staging assignment: thread loads one float4 of A and one of B per k-tile
  const int lrow  = tid >> 2;        // 0..63
  const int lcol4 = (tid & 3) << 2;  // 0,4,8,12
  const float* Arow = A + (pb * BM + lrow) * D;

  float min1[4], min2[4];
  int   idx1[4];
  #pragma unroll
  for (int i = 0; i < 4; ++i) { min1[i] = 1e30f; min2[i] = 1e30f; idx1[i] = 0; }

  for (int vt = 0; vt < VPB / BN; ++vt) {
    const int vbase = vs * VPB + vt * BN;
    float acc[4][4];
    #pragma unroll
    for (int i = 0; i < 4; ++i)
      #pragma unroll
      for (int j = 0; j < 4; ++j) acc[i][j] = 0.0f;

    for (int kt = 0; kt < D / BK; ++kt) {
      const float4 a = *(const float4*)(Arow + kt * BK + lcol4);
      const float4 b = *(const float4*)(Vc + (vbase + lrow) * D + kt * BK + lcol4);
      __syncthreads();   // previous iteration's LDS reads done
      As[lcol4 + 0][lrow] = a.x;
      As[lcol4 + 1][lrow] = a.y;
      As[lcol4 + 2][lrow] = a.z;
      As[lcol4 + 3][lrow] = a.w;
      Bs[lcol4 + 0][lrow] = b.x;
      Bs[lcol4 + 1][lrow] = b.y;
      Bs[lcol4 + 2][lrow] = b.z;
      Bs[lcol4 + 3][lrow] = b.w;
      __syncthreads();
      #pragma unroll
      for (int kk = 0; kk < BK; ++kk) {
        const float4 av = *(const float4*)&As[kk][tm << 2];
        const float4 bv = *(const float4*)&Bs[kk][tn << 2];
        const float ar[4] = {av.x, av.y, av.z, av.w};
        const float br[4] = {bv.x, bv.y, bv.z, bv.w};
        #pragma unroll
        for (int i = 0; i < 4; ++i)
          #pragma unroll
          for (int j = 0; j < 4; ++j)
            acc[i][j] = fmaf(ar[i], br[j], acc[i][j]);
      }
    }

    // score + running top-2 (thread-local candidates are index-ascending)
    #pragma unroll
    for (int j = 0; j < 4; ++j) {
      const int vg = vbase + (tn << 2) + j;
      const float vv = v2[vg];
      #pragma unroll
      for (int i = 0; i < 4; ++i) {
        const float s = fmaf(-2.0f, acc[i][j], vv);
        if (s < min1[i]) { min2[i] = min1[i]; min1[i] = s; idx1[i] = vg; }
        else if (s < min2[i]) { min2[i] = s; }
      }
    }
  }

  // block-level top-2 merge across the 16 column-thread groups
  __syncthreads();
  #pragma unroll
  for (int i = 0; i < 4; ++i) {
    sm1[(tm << 2) + i][tn] = min1[i];
    sm2[(tm << 2) + i][tn] = min2[i];
    si1[(tm << 2) + i][tn] = idx1[i];
  }
  __syncthreads();
  if (tid < BM) {
    float m1 = 1e30f, m2 = 1e30f;
    int i1 = 0x7fffffff;
    #pragma unroll
    for (int c = 0; c < 16; ++c) {
      const float b1 = sm1[tid][c], b2 = sm2[tid][c];
      const int   bi = si1[tid][c];
      if (b1 < m1 || (b1 == m1 && bi < i1)) {
        m2 = fminf(m1, b2); m1 = b1; i1 = bi;
      } else {
        m2 = fminf(m2, b1);
      }
    }
    const int gm = pb * BM + tid;
    pmin1[gm * VSPLIT + vs] = m1;
    pmin2[gm * VSPLIT + vs] = m2;
    pidx [gm * VSPLIT + vs] = i1;
  }
}

// ---------------------------------------------------------------------------
// Kernel 4: merge VSPLIT partials per patch -> token (float) + refine flag
// ---------------------------------------------------------------------------
__global__ __launch_bounds__(256) void reduce_kernel(
    const float* __restrict__ pmin1, const float* __restrict__ pmin2,
    const int* __restrict__ pidx,
    float* __restrict__ tok_out, int* __restrict__ flags) {
  const int m = blockIdx.x * blockDim.x + threadIdx.x;  // 0..M-1
  float m1 = 1e30f, m2 = 1e30f;
  int i1 = 0x7fffffff;
  #pragma unroll
  for (int vsp = 0; vsp < VSPLIT; ++vsp) {
    const float b1 = pmin1[m * VSPLIT + vsp];
    const float b2 = pmin2[m * VSPLIT + vsp];
    const int   bi = pidx [m * VSPLIT + vsp];
    if (b1 < m1 || (b1 == m1 && bi < i1)) {
      m2 = fminf(m1, b2); m1 = b1; i1 = bi;
    } else {
      m2 = fminf(m2, b1);
    }
  }
  tok_out[m] = (float)i1;
  flags[m] = (m2 - m1 < MARGIN) ? 1 : 0;
}

// ---------------------------------------------------------------------------
// Kernel 5: exact fp64 rescoring for near-tie patches (~1% expected).
// One block per patch; non-flagged blocks exit immediately.
// fp64 rounding (~1e-13) vs typical gap (~6.5): flip probability negligible.
// ---------------------------------------------------------------------------
__global__ __launch_bounds__(256) void refine_kernel(
    const float* __restrict__ patches, const float* __restrict__ vocab,
    const int* __restrict__ flags, float* __restrict__ tok_out) {
  const int m = blockIdx.x;
  if (!flags[m]) return;   // uniform per block

  __shared__ float  p[D];
  __shared__ double rbest[256];
  __shared__ int    ridx[256];
  const int tid = threadIdx.x;
  p[tid] = patches[m * D + tid];
  __syncthreads();

  double best = 1e300;
  int bidx = 0x7fffffff;
  for (int r = 0; r < V / 256; ++r) {
    const int v = r * 256 + tid;            // ascending per thread
    const float* vr = vocab + v * D;
    double acc = 0.0;
    for (int d = 0; d < D; d += 4) {
      const float4 vv = *(const float4*)(vr + d);
      double df;
      df = (double)p[d + 0] - (double)vv.x; acc = fma(df, df, acc);
      df = (double)p[d + 1] - (double)vv.y; acc = fma(df, df, acc);
      df = (double)p[d + 2] - (double)vv.z; acc = fma(df, df, acc);
      df = (double)p[d + 3] - (double)vv.w; acc = fma(df, df, acc);
    }
    if (acc < best) { best = acc; bidx = v; }  // strict <: keeps first (v ascending)
  }
  rbest[tid] = best; ridx[tid] = bidx;
  __syncthreads();
  for (int s = 128; s > 0; s >>= 1) {
    if (tid < s) {
      if (rbest[tid + s] < rbest[tid] ||
          (rbest[tid + s] == rbest[tid] && ridx[tid + s] < ridx[tid])) {
        rbest[tid] = rbest[tid + s]; ridx[tid] = ridx[tid + s];
      }
    }
    __syncthreads();
  }
  if (tid == 0) tok_out[m] = (float)ridx[0];
}

// ---------------------------------------------------------------------------
extern "C" void kernel_launch(void* const* d_in, const int* in_sizes, int n_in,
                              void* d_out, int out_size, void* d_ws, size_t ws_size,
                              hipStream_t stream) {
  const float* images = (const float*)d_in[0];   // [64,256,256]
  const float* vocab  = (const float*)d_in[1];   // [4096,256]
  float* out     = (float*)d_out;
  float* patches = out;            // M*D floats
  float* tokens  = out + M * D;    // M floats (token index as float)

  // workspace layout (floats): v2[4096] | pmin1[M*VS] | pmin2[M*VS] | pidx[M*VS] | flags[M]
  // total = 4096 + 3*65536 + 16384 = 217088 elems = 868 KB
  float* ws    = (float*)d_ws;
  float* v2    = ws;
  float* pmin1 = ws + V;
  float* pmin2 = pmin1 + M * VSPLIT;
  int*   pidx  = (int*)(pmin2 + M * VSPLIT);
  int*   flags = pidx + M * VSPLIT;

  patchify_kernel<<<(M * D / 4) / 256, 256, 0, stream>>>(images, patches);
  v2_kernel<<<(V * 64) / 256, 256, 0, stream>>>(vocab, v2);
  score_kernel<<<dim3(M / BM, VSPLIT), 256, 0, stream>>>(patches, vocab, v2,
                                                         pmin1, pmin2, pidx);
  reduce_kernel<<<M / 256, 256, 0, stream>>>(pmin1, pmin2, pidx, tokens, flags);
  refine_kernel<<<M, 256, 0, stream>>>(patches, vocab, flags, tokens);
}

// Round 2
// 419.805 us; speedup vs baseline: 2.2446x; 2.2446x over previous
//
#include <hip/hip_runtime.h>
#include <math.h>

// Problem: images [64,256,256] f32 -> patches [16384][256] f32 (identity perm)
//          tokens [16384] = argmin_v ||patch - vocab[v]||^2, vocab [4096][256] f32
#define PS      16
#define D       256
#define V       4096
#define M       16384
#define NCB     32              // V / 128 column blocks
// fp16 single-pass score error: sd ~1.3e-2, <=6e-2 at 5 sigma; margin 0.25 = ~19 sigma.
// Expected flag fraction ~3% (top-2 gap ~Exp(mean 9)); flagged patches get exact fp64.
#define MARGIN  0.25f

typedef _Float16 half8 __attribute__((ext_vector_type(8)));
typedef _Float16 half4 __attribute__((ext_vector_type(4)));
typedef float    f32x4 __attribute__((ext_vector_type(4)));

__device__ __forceinline__ void gload_lds16(const void* g, void* l) {
  __builtin_amdgcn_global_load_lds(
      (const __attribute__((address_space(1))) unsigned int*)g,
      (__attribute__((address_space(3))) unsigned int*)l, 16, 0, 0);
}

// ---------------------------------------------------------------------------
// Kernel 1: patchify (float4) + fp16 copy of patches for the MFMA GEMM.
// ---------------------------------------------------------------------------
__global__ __launch_bounds__(256) void patchify_half_kernel(
    const float* __restrict__ img, float* __restrict__ outp,
    _Float16* __restrict__ Ah) {
  const int t  = blockIdx.x * 256 + threadIdx.x;   // M*D/4 threads
  const int o4 = t << 2;
  const int b   = o4 >> 16;
  const int rem = o4 & 65535;
  const int n   = rem >> 8;
  const int d   = rem & 255;
  const int py = n >> 4, px = n & 15, i = d >> 4, j = d & 15;
  const float4 v = *(const float4*)(img + (b << 16) + ((py * PS + i) << 8) + px * PS + j);
  *(float4*)(outp + o4) = v;
  half4 h = { (_Float16)v.x, (_Float16)v.y, (_Float16)v.z, (_Float16)v.w };
  *(half4*)(Ah + o4) = h;
}

// ---------------------------------------------------------------------------
// Kernel 2: vocab -> fp16 copy
// ---------------------------------------------------------------------------
__global__ __launch_bounds__(256) void vocab_half_kernel(
    const float* __restrict__ vocab, _Float16* __restrict__ Vh) {
  const int t  = blockIdx.x * 256 + threadIdx.x;   // V*D/4 threads
  const int o4 = t << 2;
  const float4 v = *(const float4*)(vocab + o4);
  half4 h = { (_Float16)v.x, (_Float16)v.y, (_Float16)v.z, (_Float16)v.w };
  *(half4*)(Vh + o4) = h;
}

// ---------------------------------------------------------------------------
// Kernel 3: v2[v] = sum_d vocab[v][d]^2  (fp32, one wave per row)
// ---------------------------------------------------------------------------
__global__ __launch_bounds__(256) void v2_kernel(
    const float* __restrict__ vocab, float* __restrict__ v2) {
  const int gtid = blockIdx.x * 256 + threadIdx.x;
  const int row  = gtid >> 6;
  const int lane = gtid & 63;
  const float4 x = *(const float4*)(vocab + row * D + (lane << 2));
  float s = x.x * x.x + x.y * x.y + x.z * x.z + x.w * x.w;
  #pragma unroll
  for (int off = 32; off > 0; off >>= 1) s += __shfl_down(s, off);
  if (lane == 0) v2[row] = s;
}

// ---------------------------------------------------------------------------
// Kernel 4: fp16 MFMA score GEMM, 128x128 tile, BK=32, K=256.
// score = v2[v] - 2 * dot(patch, vocab[v]); per-row top-2 over the block's
// 128 cols -> partials [NCB][M] (transposed for coalescing).
// LDS granule XOR swizzle (p = q ^ ((row>>1)&3)) -> frag ds_read_b128 is
// 2-way max (free); global_load_lds lane assignment applies the inverse.
// ---------------------------------------------------------------------------
__global__ __launch_bounds__(256) void gemm_score_kernel(
    const _Float16* __restrict__ Ah,   // [M][256]
    const _Float16* __restrict__ Vh,   // [V][256]
    const float* __restrict__ v2,
    float* __restrict__ pmin1, float* __restrict__ pmin2,
    int* __restrict__ pidx) {
  __shared__ __align__(16) _Float16 As[128 * 32];
  __shared__ __align__(16) _Float16 Bs[128 * 32];
  __shared__ float eM1[128][2];
  __shared__ float eM2[128][2];
  __shared__ int   eI [128][2];

  const int tid  = threadIdx.x;
  const int lane = tid & 63;
  const int wid  = tid >> 6;          // 4 waves, 2x2 layout
  const int waveRow = wid >> 1;
  const int waveCol = wid & 1;
  const int row0 = blockIdx.x * 128;
  const int col0 = blockIdx.y * 128;

  // staging: inst (wid,i) covers rows wid*32 + i*16 .. +15 of the tile.
  // lane -> row (lane>>2), LDS granule (lane&3); fetches global granule
  // (lane&3) ^ ((row>>1)&3) so LDS position p holds granule p ^ ((row>>1)&3).
  const int srow  = lane >> 2;
  const int sgran = ((lane & 3) ^ ((lane >> 3) & 3)) << 4;  // byte off in 64B row
  const char* Ag0 = (const char*)(Ah + (size_t)(row0 + wid * 32 + srow) * D) + sgran;
  const char* Bg0 = (const char*)(Vh + (size_t)(col0 + wid * 32 + srow) * D) + sgran;
  _Float16* Al0 = As + wid * 32 * 32;
  _Float16* Bl0 = Bs + wid * 32 * 32;

  f32x4 acc[4][4];
  #pragma unroll
  for (int i = 0; i < 4; ++i)
    #pragma unroll
    for (int j = 0; j < 4; ++j) acc[i][j] = (f32x4){0.f, 0.f, 0.f, 0.f};

  const int cl = lane & 15;           // fragment row/col within 16
  const int q  = lane >> 4;           // quad: k-chunk selector
  const int fgran = (q ^ ((cl >> 1) & 3)) << 3;  // halves offset in 32-half row

  for (int kt = 0; kt < D / 32; ++kt) {
    const int go = kt * 64;           // bytes along K
    gload_lds16(Ag0 + go,            Al0);
    gload_lds16(Ag0 + 16 * 512 + go, Al0 + 16 * 32);
    gload_lds16(Bg0 + go,            Bl0);
    gload_lds16(Bg0 + 16 * 512 + go, Bl0 + 16 * 32);
    __syncthreads();                  // drains vmcnt: tiles resident
    half8 af[4], bf[4];
    #pragma unroll
    for (int f = 0; f < 4; ++f) {
      af[f] = *(const half8*)(As + (waveRow * 64 + f * 16 + cl) * 32 + fgran);
      bf[f] = *(const half8*)(Bs + (waveCol * 64 + f * 16 + cl) * 32 + fgran);
    }
    #pragma unroll
    for (int i = 0; i < 4; ++i)
      #pragma unroll
      for (int j = 0; j < 4; ++j)
        acc[i][j] = __builtin_amdgcn_mfma_f32_16x16x32_f16(af[i], bf[j], acc[i][j], 0, 0, 0);
    __syncthreads();                  // LDS reads done before next overwrite
  }

  // Epilogue: C/D layout col=lane&15, row=quad*4+reg (m89/m91-verified).
  float v2r[4];
  #pragma unroll
  for (int j = 0; j < 4; ++j) v2r[j] = v2[col0 + waveCol * 64 + j * 16 + cl];

  #pragma unroll
  for (int i = 0; i < 4; ++i) {       // fragment row block
    #pragma unroll
    for (int r = 0; r < 4; ++r) {     // acc register -> row quad*4+r
      float m1 = 1e30f, m2 = 1e30f;
      int   i1 = 0x7fffffff;
      #pragma unroll
      for (int j = 0; j < 4; ++j) {
        const float s = fmaf(-2.0f, acc[i][j][r], v2r[j]);
        const int   c = col0 + waveCol * 64 + j * 16 + cl;
        if (s < m1 || (s == m1 && c < i1)) { m2 = m1; m1 = s; i1 = c; }
        else m2 = fminf(m2, s);
      }
      // butterfly top-2 merge across the 16 lanes holding this row
      #pragma unroll
      for (int mask = 1; mask <= 8; mask <<= 1) {
        const float om1 = __shfl_xor(m1, mask);
        const float om2 = __shfl_xor(m2, mask);
        const int   oi1 = __shfl_xor(i1, mask);
        if (om1 < m1 || (om1 == m1 && oi1 < i1)) {
          m2 = fminf(m1, om2); m1 = om1; i1 = oi1;
        } else {
          m2 = fminf(m2, om1);
        }
      }
      if (cl == 0) {
        const int rl = waveRow * 64 + i * 16 + q * 4 + r;
        eM1[rl][waveCol] = m1; eM2[rl][waveCol] = m2; eI[rl][waveCol] = i1;
      }
    }
  }
  __syncthreads();
  if (tid < 128) {
    const float a1 = eM1[tid][0], a2 = eM2[tid][0];
    const float b1 = eM1[tid][1], b2 = eM2[tid][1];
    const int   ai = eI[tid][0],  bi = eI[tid][1];
    float m1, m2; int i1;
    if (b1 < a1 || (b1 == a1 && bi < ai)) { m1 = b1; i1 = bi; m2 = fminf(b2, a1); }
    else                                  { m1 = a1; i1 = ai; m2 = fminf(a2, b1); }
    const int gm = row0 + tid;
    pmin1[(size_t)blockIdx.y * M + gm] = m1;
    pmin2[(size_t)blockIdx.y * M + gm] = m2;
    pidx [(size_t)blockIdx.y * M + gm] = i1;
  }
}

// ---------------------------------------------------------------------------
// Kernel 5: merge NCB partials per patch -> token + compacted refine worklist
// ---------------------------------------------------------------------------
__global__ __launch_bounds__(256) void reduce_kernel(
    const float* __restrict__ pmin1, const float* __restrict__ pmin2,
    const int* __restrict__ pidx, float* __restrict__ tok,
    int* __restrict__ rlist, int* __restrict__ rcount) {
  const int m = blockIdx.x * 256 + threadIdx.x;
  float m1 = 1e30f, m2 = 1e30f;
  int i1 = 0x7fffffff;
  #pragma unroll
  for (int cb = 0; cb < NCB; ++cb) {
    const float b1 = pmin1[(size_t)cb * M + m];
    const float b2 = pmin2[(size_t)cb * M + m];
    const int   bi = pidx [(size_t)cb * M + m];
    if (b1 < m1 || (b1 == m1 && bi < i1)) { m2 = fminf(m1, b2); m1 = b1; i1 = bi; }
    else m2 = fminf(m2, b1);
  }
  tok[m] = (float)i1;
  if (m2 - m1 < MARGIN) {
    const int pos = atomicAdd(rcount, 1);
    rlist[pos] = m;
  }
}

// ---------------------------------------------------------------------------
// Kernel 6: exact fp64 rescore of flagged patches (grid-stride over worklist)
// ---------------------------------------------------------------------------
__global__ __launch_bounds__(256) void refine_kernel(
    const float* __restrict__ patches, const float* __restrict__ vocab,
    const int* __restrict__ rlist, const int* __restrict__ rcount,
    float* __restrict__ tok) {
  __shared__ float  p[D];
  __shared__ double rb[256];
  __shared__ int    ri[256];
  const int tid = threadIdx.x;
  const int n = *rcount;
  for (int e = blockIdx.x; e < n; e += gridDim.x) {
    const int m = rlist[e];
    __syncthreads();                     // protect p[] reuse across entries
    p[tid] = patches[(size_t)m * D + tid];
    __syncthreads();
    double best = 1e300;
    int bidx = 0x7fffffff;
    for (int r = 0; r < V / 256; ++r) {
      const int v = r * 256 + tid;       // ascending per thread
      const float* vr = vocab + (size_t)v * D;
      double acc2 = 0.0;
      for (int d = 0; d < D; d += 4) {
        const float4 vv = *(const float4*)(vr + d);
        double df;
        df = (double)p[d + 0] - (double)vv.x; acc2 = fma(df, df, acc2);
        df = (double)p[d + 1] - (double)vv.y; acc2 = fma(df, df, acc2);
        df = (double)p[d + 2] - (double)vv.z; acc2 = fma(df, df, acc2);
        df = (double)p[d + 3] - (double)vv.w; acc2 = fma(df, df, acc2);
      }
      if (acc2 < best) { best = acc2; bidx = v; }  // strict <: first occurrence
    }
    rb[tid] = best; ri[tid] = bidx;
    __syncthreads();
    for (int s = 128; s > 0; s >>= 1) {
      if (tid < s) {
        if (rb[tid + s] < rb[tid] ||
            (rb[tid + s] == rb[tid] && ri[tid + s] < ri[tid])) {
          rb[tid] = rb[tid + s]; ri[tid] = ri[tid + s];
        }
      }
      __syncthreads();
    }
    if (tid == 0) tok[m] = (float)ri[0];
  }
}

// ---------------------------------------------------------------------------
extern "C" void kernel_launch(void* const* d_in, const int* in_sizes, int n_in,
                              void* d_out, int out_size, void* d_ws, size_t ws_size,
                              hipStream_t stream) {
  const float* images = (const float*)d_in[0];   // [64,256,256]
  const float* vocab  = (const float*)d_in[1];   // [4096,256]
  float* out     = (float*)d_out;
  float* patches = out;            // M*D floats
  float* tokens  = out + (size_t)M * D;

  // workspace layout (bytes):
  // Ah 8MB | Vh 2MB | v2 16KB | pmin1 2MB | pmin2 2MB | pidx 2MB | rlist 64KB | rcount
  char* ws = (char*)d_ws;
  _Float16* Ah   = (_Float16*)(ws);
  _Float16* Vh   = (_Float16*)(ws + 8388608);
  float*    v2   = (float*)   (ws + 10485760);
  float*   pmin1 = (float*)   (ws + 10502144);
  float*   pmin2 = (float*)   (ws + 12599296);
  int*     pidx  = (int*)     (ws + 14696448);
  int*     rlist = (int*)     (ws + 16793600);
  int*     rcount= (int*)     (ws + 16859136);

  hipMemsetAsync(rcount, 0, sizeof(int), stream);
  patchify_half_kernel<<<(M * D / 4) / 256, 256, 0, stream>>>(images, patches, Ah);
  vocab_half_kernel<<<(V * D / 4) / 256, 256, 0, stream>>>(vocab, Vh);
  v2_kernel<<<(V * 64) / 256, 256, 0, stream>>>(vocab, v2);
  gemm_score_kernel<<<dim3(M / 128, V / 128), 256, 0, stream>>>(Ah, Vh, v2,
                                                                pmin1, pmin2, pidx);
  reduce_kernel<<<M / 256, 256, 0, stream>>>(pmin1, pmin2, pidx, tokens,
                                             rlist, rcount);
  refine_kernel<<<1024, 256, 0, stream>>>(patches, vocab, rlist, rcount, tokens);
}

// Round 3
// 241.603 us; speedup vs baseline: 3.9001x; 1.7376x over previous
//
#include <hip/hip_runtime.h>
#include <math.h>

// Problem: images [64,256,256] f32 -> patches [16384][256] f32 (identity perm)
//          tokens [16384] = argmin_v ||patch - vocab[v]||^2, vocab [4096][256] f32
#define PS      16
#define D       256
#define V       4096
#define M       16384
#define NCB     32              // V / 128 column blocks
// fp16 input-quantization score error: sigma ~3.1e-2. MARGIN = 0.5 = 16 sigma;
// exclusion guarantee needs MARGIN > 2*E with E = 8 sigma -> P(miss) ~1e-8 over
// all 6.7e7 scores. Flag rate ~5%; flagged patches get exact fp64 on a tiny
// candidate list derived from per-block top-2 partials.
#define MARGIN  0.5f

typedef _Float16 half8 __attribute__((ext_vector_type(8)));
typedef _Float16 half4 __attribute__((ext_vector_type(4)));
typedef float    f32x4 __attribute__((ext_vector_type(4)));

__device__ __forceinline__ void gload_lds16(const void* g, void* l) {
  __builtin_amdgcn_global_load_lds(
      (const __attribute__((address_space(1))) unsigned int*)g,
      (__attribute__((address_space(3))) unsigned int*)l, 16, 0, 0);
}

// ---------------------------------------------------------------------------
// Kernel 1: patchify (float4) + fp16 copy of patches for the MFMA GEMM.
// ---------------------------------------------------------------------------
__global__ __launch_bounds__(256) void patchify_half_kernel(
    const float* __restrict__ img, float* __restrict__ outp,
    _Float16* __restrict__ Ah) {
  const int t  = blockIdx.x * 256 + threadIdx.x;   // M*D/4 threads
  const int o4 = t << 2;
  const int b   = o4 >> 16;
  const int rem = o4 & 65535;
  const int n   = rem >> 8;
  const int d   = rem & 255;
  const int py = n >> 4, px = n & 15, i = d >> 4, j = d & 15;
  const float4 v = *(const float4*)(img + (b << 16) + ((py * PS + i) << 8) + px * PS + j);
  *(float4*)(outp + o4) = v;
  half4 h = { (_Float16)v.x, (_Float16)v.y, (_Float16)v.z, (_Float16)v.w };
  *(half4*)(Ah + o4) = h;
}

// ---------------------------------------------------------------------------
// Kernel 2: vocab -> fp16 copy + v2[v] = sum_d vocab[v][d]^2 (one wave / row)
// ---------------------------------------------------------------------------
__global__ __launch_bounds__(256) void vocab_half_v2_kernel(
    const float* __restrict__ vocab, _Float16* __restrict__ Vh,
    float* __restrict__ v2) {
  const int gtid = blockIdx.x * 256 + threadIdx.x;
  const int row  = gtid >> 6;
  const int lane = gtid & 63;
  const float4 v = *(const float4*)(vocab + (size_t)row * D + (lane << 2));
  half4 h = { (_Float16)v.x, (_Float16)v.y, (_Float16)v.z, (_Float16)v.w };
  *(half4*)(Vh + (size_t)row * D + (lane << 2)) = h;
  float s = v.x * v.x + v.y * v.y + v.z * v.z + v.w * v.w;
  #pragma unroll
  for (int off = 32; off > 0; off >>= 1) s += __shfl_down(s, off);
  if (lane == 0) v2[row] = s;
}

// ---------------------------------------------------------------------------
// Kernel 3: fp16 MFMA score GEMM, 128x128 tile, BK=32, K=256.
// score = v2[v] - 2 * dot(patch, vocab[v]); per-row top-2 over the block's
// 128 cols -> partials [NCB][M] (transposed for coalescing).
// ---------------------------------------------------------------------------
__global__ __launch_bounds__(256) void gemm_score_kernel(
    const _Float16* __restrict__ Ah,   // [M][256]
    const _Float16* __restrict__ Vh,   // [V][256]
    const float* __restrict__ v2,
    float* __restrict__ pmin1, float* __restrict__ pmin2,
    int* __restrict__ pidx) {
  __shared__ __align__(16) _Float16 As[128 * 32];
  __shared__ __align__(16) _Float16 Bs[128 * 32];
  __shared__ float eM1[128][2];
  __shared__ float eM2[128][2];
  __shared__ int   eI [128][2];

  const int tid  = threadIdx.x;
  const int lane = tid & 63;
  const int wid  = tid >> 6;          // 4 waves, 2x2 layout
  const int waveRow = wid >> 1;
  const int waveCol = wid & 1;
  const int row0 = blockIdx.x * 128;
  const int col0 = blockIdx.y * 128;

  // staging: lane -> row (lane>>2), LDS granule (lane&3); fetches global
  // granule (lane&3) ^ ((row>>1)&3) so frag ds_read_b128 is 2-way max (free).
  const int srow  = lane >> 2;
  const int sgran = ((lane & 3) ^ ((lane >> 3) & 3)) << 4;  // byte off in 64B row
  const char* Ag0 = (const char*)(Ah + (size_t)(row0 + wid * 32 + srow) * D) + sgran;
  const char* Bg0 = (const char*)(Vh + (size_t)(col0 + wid * 32 + srow) * D) + sgran;
  _Float16* Al0 = As + wid * 32 * 32;
  _Float16* Bl0 = Bs + wid * 32 * 32;

  f32x4 acc[4][4];
  #pragma unroll
  for (int i = 0; i < 4; ++i)
    #pragma unroll
    for (int j = 0; j < 4; ++j) acc[i][j] = (f32x4){0.f, 0.f, 0.f, 0.f};

  const int cl = lane & 15;           // fragment row/col within 16
  const int q  = lane >> 4;           // quad: k-chunk selector
  const int fgran = (q ^ ((cl >> 1) & 3)) << 3;  // halves offset in 32-half row

  for (int kt = 0; kt < D / 32; ++kt) {
    const int go = kt * 64;           // bytes along K
    gload_lds16(Ag0 + go,            Al0);
    gload_lds16(Ag0 + 16 * 512 + go, Al0 + 16 * 32);
    gload_lds16(Bg0 + go,            Bl0);
    gload_lds16(Bg0 + 16 * 512 + go, Bl0 + 16 * 32);
    __syncthreads();                  // drains vmcnt: tiles resident
    half8 af[4], bf[4];
    #pragma unroll
    for (int f = 0; f < 4; ++f) {
      af[f] = *(const half8*)(As + (waveRow * 64 + f * 16 + cl) * 32 + fgran);
      bf[f] = *(const half8*)(Bs + (waveCol * 64 + f * 16 + cl) * 32 + fgran);
    }
    #pragma unroll
    for (int i = 0; i < 4; ++i)
      #pragma unroll
      for (int j = 0; j < 4; ++j)
        acc[i][j] = __builtin_amdgcn_mfma_f32_16x16x32_f16(af[i], bf[j], acc[i][j], 0, 0, 0);
    __syncthreads();                  // LDS reads done before next overwrite
  }

  // Epilogue: C/D layout col=lane&15, row=quad*4+reg (m89/m91-verified).
  float v2r[4];
  #pragma unroll
  for (int j = 0; j < 4; ++j) v2r[j] = v2[col0 + waveCol * 64 + j * 16 + cl];

  #pragma unroll
  for (int i = 0; i < 4; ++i) {       // fragment row block
    #pragma unroll
    for (int r = 0; r < 4; ++r) {     // acc register -> row quad*4+r
      float m1 = 1e30f, m2 = 1e30f;
      int   i1 = 0x7fffffff;
      #pragma unroll
      for (int j = 0; j < 4; ++j) {
        const float s = fmaf(-2.0f, acc[i][j][r], v2r[j]);
        const int   c = col0 + waveCol * 64 + j * 16 + cl;
        if (s < m1 || (s == m1 && c < i1)) { m2 = m1; m1 = s; i1 = c; }
        else m2 = fminf(m2, s);
      }
      // butterfly top-2 merge across the 16 lanes holding this row
      #pragma unroll
      for (int mask = 1; mask <= 8; mask <<= 1) {
        const float om1 = __shfl_xor(m1, mask);
        const float om2 = __shfl_xor(m2, mask);
        const int   oi1 = __shfl_xor(i1, mask);
        if (om1 < m1 || (om1 == m1 && oi1 < i1)) {
          m2 = fminf(m1, om2); m1 = om1; i1 = oi1;
        } else {
          m2 = fminf(m2, om1);
        }
      }
      if (cl == 0) {
        const int rl = waveRow * 64 + i * 16 + q * 4 + r;
        eM1[rl][waveCol] = m1; eM2[rl][waveCol] = m2; eI[rl][waveCol] = i1;
      }
    }
  }
  __syncthreads();
  if (tid < 128) {
    const float a1 = eM1[tid][0], a2 = eM2[tid][0];
    const float b1 = eM1[tid][1], b2 = eM2[tid][1];
    const int   ai = eI[tid][0],  bi = eI[tid][1];
    float m1, m2; int i1;
    if (b1 < a1 || (b1 == a1 && bi < ai)) { m1 = b1; i1 = bi; m2 = fminf(b2, a1); }
    else                                  { m1 = a1; i1 = ai; m2 = fminf(a2, b1); }
    const int gm = row0 + tid;
    pmin1[(size_t)blockIdx.y * M + gm] = m1;
    pmin2[(size_t)blockIdx.y * M + gm] = m2;
    pidx [(size_t)blockIdx.y * M + gm] = i1;
  }
}

// ---------------------------------------------------------------------------
// Kernel 4: merge NCB partials per patch -> token + compacted refine worklist
// ---------------------------------------------------------------------------
__global__ __launch_bounds__(256) void reduce_kernel(
    const float* __restrict__ pmin1, const float* __restrict__ pmin2,
    const int* __restrict__ pidx, float* __restrict__ tok,
    int* __restrict__ rlist, int* __restrict__ rcount) {
  const int m = blockIdx.x * 256 + threadIdx.x;
  float m1 = 1e30f, m2 = 1e30f;
  int i1 = 0x7fffffff;
  #pragma unroll
  for (int cb = 0; cb < NCB; ++cb) {
    const float b1 = pmin1[(size_t)cb * M + m];
    const float b2 = pmin2[(size_t)cb * M + m];
    const int   bi = pidx [(size_t)cb * M + m];
    if (b1 < m1 || (b1 == m1 && bi < i1)) { m2 = fminf(m1, b2); m1 = b1; i1 = bi; }
    else m2 = fminf(m2, b1);
  }
  tok[m] = (float)i1;
  if (m2 - m1 < MARGIN) {
    const int pos = atomicAdd(rcount, 1);
    rlist[pos] = m;
  }
}

// ---------------------------------------------------------------------------
// Kernel 5: exact fp64 rescore of flagged patches over a tiny candidate list.
// Candidates: per column block, its i1 if m1_b < thresh; full 128-row block
// scan only if m2_b < thresh (a block can hide an unseen contender only then).
// One wave per candidate row: 64 lanes x 4 dims, fp64 shuffle-reduce.
// ---------------------------------------------------------------------------
__global__ __launch_bounds__(256) void refine_kernel(
    const float* __restrict__ patches, const float* __restrict__ vocab,
    const float* __restrict__ pmin1, const float* __restrict__ pmin2,
    const int* __restrict__ pidx,
    const int* __restrict__ rlist, const int* __restrict__ rcount,
    float* __restrict__ tok) {
  __shared__ float  p[D];
  __shared__ int    rows[V];       // worst case: all 32 blocks scanned
  __shared__ double scores[V / 8]; // scored in chunks of <=512 rows
  __shared__ int    nrows_s;
  __shared__ float  thresh_s;
  const int tid  = threadIdx.x;
  const int lane = tid & 63;
  const int w    = tid >> 6;
  const int n = *rcount;
  for (int e = blockIdx.x; e < n; e += gridDim.x) {
    const int m = rlist[e];
    __syncthreads();                     // protect LDS reuse across entries
    if (tid == 0) nrows_s = 0;
    p[tid] = patches[(size_t)m * D + tid];
    // wave 0: global m1 over the 32 block partials -> thresh
    float b1 = 1e30f, b2 = 1e30f;
    int bi = 0;
    if (tid < NCB) {
      b1 = pmin1[(size_t)tid * M + m];
      b2 = pmin2[(size_t)tid * M + m];
      bi = pidx [(size_t)tid * M + m];
    }
    if (w == 0) {
      float t1 = b1;
      #pragma unroll
      for (int off = 16; off > 0; off >>= 1) t1 = fminf(t1, __shfl_down(t1, off));
      const float th = __shfl(t1, 0) + MARGIN;
      if (lane == 0) thresh_s = th;
    }
    __syncthreads();
    const float th = thresh_s;
    if (tid < NCB) {
      if (b2 < th) {                     // block may hide a 3rd contender: scan it
        const int base = atomicAdd(&nrows_s, 128);
        for (int r = 0; r < 128; ++r) rows[base + r] = tid * 128 + r;
      } else if (b1 < th) {              // only the stored winner qualifies
        const int pos = atomicAdd(&nrows_s, 1);
        rows[pos] = bi;
      }
    }
    __syncthreads();
    const int nr = nrows_s;
    double best = 1e300;
    int bestrow = 0x7fffffff;
    for (int c0 = 0; c0 < nr; c0 += V / 8) {
      const int ce = min(nr, c0 + V / 8);
      for (int r = c0 + w; r < ce; r += 4) {
        const int row = rows[r];
        const float4 vv = *(const float4*)(vocab + (size_t)row * D + (lane << 2));
        double acc = 0.0, df;
        df = (double)p[(lane << 2) + 0] - (double)vv.x; acc = fma(df, df, acc);
        df = (double)p[(lane << 2) + 1] - (double)vv.y; acc = fma(df, df, acc);
        df = (double)p[(lane << 2) + 2] - (double)vv.z; acc = fma(df, df, acc);
        df = (double)p[(lane << 2) + 3] - (double)vv.w; acc = fma(df, df, acc);
        #pragma unroll
        for (int off = 32; off > 0; off >>= 1) acc += __shfl_down(acc, off);
        if (lane == 0) scores[r - c0] = acc;
      }
      __syncthreads();
      if (tid == 0) {
        for (int r = c0; r < ce; ++r) {
          const double s = scores[r - c0];
          const int    rw = rows[r];
          if (s < best || (s == best && rw < bestrow)) { best = s; bestrow = rw; }
        }
      }
      __syncthreads();
    }
    if (tid == 0) tok[m] = (float)bestrow;
  }
}

// ---------------------------------------------------------------------------
extern "C" void kernel_launch(void* const* d_in, const int* in_sizes, int n_in,
                              void* d_out, int out_size, void* d_ws, size_t ws_size,
                              hipStream_t stream) {
  const float* images = (const float*)d_in[0];   // [64,256,256]
  const float* vocab  = (const float*)d_in[1];   // [4096,256]
  float* out     = (float*)d_out;
  float* patches = out;            // M*D floats
  float* tokens  = out + (size_t)M * D;

  // workspace layout (bytes):
  // Ah 8MB | Vh 2MB | v2 16KB | pmin1 2MB | pmin2 2MB | pidx 2MB | rlist 64KB | rcount
  char* ws = (char*)d_ws;
  _Float16* Ah   = (_Float16*)(ws);
  _Float16* Vh   = (_Float16*)(ws + 8388608);
  float*    v2   = (float*)   (ws + 10485760);
  float*   pmin1 = (float*)   (ws + 10502144);
  float*   pmin2 = (float*)   (ws + 12599296);
  int*     pidx  = (int*)     (ws + 14696448);
  int*     rlist = (int*)     (ws + 16793600);
  int*     rcount= (int*)     (ws + 16859136);

  hipMemsetAsync(rcount, 0, sizeof(int), stream);
  patchify_half_kernel<<<(M * D / 4) / 256, 256, 0, stream>>>(images, patches, Ah);
  vocab_half_v2_kernel<<<(V * 64) / 256, 256, 0, stream>>>(vocab, Vh, v2);
  gemm_score_kernel<<<dim3(M / 128, V / 128), 256, 0, stream>>>(Ah, Vh, v2,
                                                                pmin1, pmin2, pidx);
  reduce_kernel<<<M / 256, 256, 0, stream>>>(pmin1, pmin2, pidx, tokens,
                                             rlist, rcount);
  refine_kernel<<<512, 256, 0, stream>>>(patches, vocab, pmin1, pmin2, pidx,
                                         rlist, rcount, tokens);
}